// Round 5
// baseline (168.869 us; speedup 1.0000x reference)
//
#include <hip/hip_runtime.h>
#include <hip/hip_bf16.h>

typedef unsigned short u16;
typedef __bf16 bf16x8 __attribute__((ext_vector_type(8)));
typedef float f32x4 __attribute__((ext_vector_type(4)));
typedef float f32x16 __attribute__((ext_vector_type(16)));
typedef unsigned short u16x8 __attribute__((ext_vector_type(8)));
typedef unsigned short u16x4 __attribute__((ext_vector_type(4)));

// S=128, R=256, CM=256, CZ=128, H=8, HD=32

__device__ __forceinline__ u16 f2bf(float f) {
  union { float f; unsigned u; } v; v.f = f;
  unsigned r = v.u;
  r += 0x7fffu + ((r >> 16) & 1u);   // RNE
  return (u16)(r >> 16);
}
__device__ __forceinline__ float bf2f(u16 u) {
  union { unsigned u; float f; } v; v.u = ((unsigned)u) << 16;
  return v.f;
}

// ---------------------------------------------------------------------------
// Kernel 0: weights fp32 [k][n] -> bf16 transposed [n][k], via LDS 64x64 tile.
__global__ __launch_bounds__(256) void k_prep_w(
    const float* __restrict__ wq, const float* __restrict__ wk,
    const float* __restrict__ wv, const float* __restrict__ wg,
    const float* __restrict__ wo, u16* __restrict__ dst) {
  const int widx = blockIdx.x >> 4;
  const int tid = blockIdx.x & 15;
  const int ri = (tid >> 2) * 64;   // k-origin
  const int ci = (tid & 3) * 64;    // n-origin
  const float* src = (widx == 0) ? wq : (widx == 1) ? wk : (widx == 2) ? wv
                    : (widx == 3) ? wg : wo;
  __shared__ float lt[64][68];
  const int t = threadIdx.x;
  const int r = t >> 2;
  #pragma unroll
  for (int i = 0; i < 4; ++i) {
    const int c = (t & 3) * 16 + i * 4;
    *(float4*)&lt[r][c] = *(const float4*)&src[(ri + r) * 256 + ci + c];
  }
  __syncthreads();
  const int nl = t >> 2, kc = (t & 3) * 16;
  u16x8 o0, o1;
  #pragma unroll
  for (int j = 0; j < 8; ++j) o0[j] = f2bf(lt[kc + j][nl]);
  #pragma unroll
  for (int j = 0; j < 8; ++j) o1[j] = f2bf(lt[kc + 8 + j][nl]);
  u16* drow = dst + (size_t)widx * 65536 + (size_t)(ci + nl) * 256 + ri + kc;
  *(u16x8*)&drow[0] = o0;
  *(u16x8*)&drow[8] = o1;
}

// ---------------------------------------------------------------------------
// Kernel 1: pair bias -> PERMUTED layout pbp (MFMA-D order).
__global__ __launch_bounds__(256) void k_pair_bias(
    const float* __restrict__ z, const float* __restrict__ zg,
    const float* __restrict__ zb, const float* __restrict__ wz,
    float* __restrict__ pbp) {
  const int t = threadIdx.x;
  const int lane = t & 63, wave = t >> 6;
  const int ql = lane & 15;
  const int p = blockIdx.x * 16 + wave * 4 + (lane >> 4);   // i*256+j
  const float4 zv0 = *(const float4*)(z + (size_t)p * 128 + ql * 8);
  const float4 zv1 = *(const float4*)(z + (size_t)p * 128 + ql * 8 + 4);
  float s = zv0.x + zv0.y + zv0.z + zv0.w + zv1.x + zv1.y + zv1.z + zv1.w;
  float sq = zv0.x * zv0.x + zv0.y * zv0.y + zv0.z * zv0.z + zv0.w * zv0.w
           + zv1.x * zv1.x + zv1.y * zv1.y + zv1.z * zv1.z + zv1.w * zv1.w;
  #pragma unroll
  for (int o = 8; o > 0; o >>= 1) { s += __shfl_xor(s, o); sq += __shfl_xor(sq, o); }
  const float mu = s * 0.0078125f;
  const float var = sq * 0.0078125f - mu * mu;
  const float rs = rsqrtf(var + 1e-5f);
  const int c0 = ql * 8;
  float zn[8];
  zn[0] = (zv0.x - mu) * rs * zg[c0 + 0] + zb[c0 + 0];
  zn[1] = (zv0.y - mu) * rs * zg[c0 + 1] + zb[c0 + 1];
  zn[2] = (zv0.z - mu) * rs * zg[c0 + 2] + zb[c0 + 2];
  zn[3] = (zv0.w - mu) * rs * zg[c0 + 3] + zb[c0 + 3];
  zn[4] = (zv1.x - mu) * rs * zg[c0 + 4] + zb[c0 + 4];
  zn[5] = (zv1.y - mu) * rs * zg[c0 + 5] + zb[c0 + 5];
  zn[6] = (zv1.z - mu) * rs * zg[c0 + 6] + zb[c0 + 6];
  zn[7] = (zv1.w - mu) * rs * zg[c0 + 7] + zb[c0 + 7];
  float a[8] = {};
  #pragma unroll
  for (int i = 0; i < 8; ++i) {
    #pragma unroll
    for (int hh = 0; hh < 8; ++hh) a[hh] += zn[i] * wz[(c0 + i) * 8 + hh];
  }
  #pragma unroll
  for (int hh = 0; hh < 8; ++hh) {
    #pragma unroll
    for (int o = 8; o > 0; o >>= 1) a[hh] += __shfl_xor(a[hh], o);
  }
  if (ql == 0) {
    const int i = p >> 8, j = p & 255;
    const int strip = i >> 5, il = i & 31, jt = j >> 5, r = j & 31;
    const int gh = (r >> 2) & 1, qd = r >> 3, c4 = r & 3;
    const int off = (strip * 8 + jt) * 1024 + (gh * 32 + il) * 16 + qd * 4 + c4;
    #pragma unroll
    for (int hh = 0; hh < 8; ++hh) pbp[(size_t)hh * 65536 + off] = a[hh];
  }
}

// ---------------------------------------------------------------------------
// Kernel 2: LayerNorm(m) -> bf16 [32768][256]. One wave per row.
__global__ __launch_bounds__(256) void k_ln_m(
    const float* __restrict__ m, const float* __restrict__ gam,
    const float* __restrict__ bet, u16* __restrict__ mln) {
  const int lane = threadIdx.x & 63;
  const size_t row = (size_t)blockIdx.x * 4 + (threadIdx.x >> 6);
  const float4 xv = *(const float4*)(m + row * 256 + lane * 4);
  float s = xv.x + xv.y + xv.z + xv.w;
  float sq = xv.x * xv.x + xv.y * xv.y + xv.z * xv.z + xv.w * xv.w;
  #pragma unroll
  for (int o = 32; o > 0; o >>= 1) { s += __shfl_xor(s, o); sq += __shfl_xor(sq, o); }
  const float mu = s * 0.00390625f;
  const float var = sq * 0.00390625f - mu * mu;
  const float rs = rsqrtf(var + 1e-5f);
  const int c = lane * 4;
  u16x4 o4;
  o4.x = f2bf((xv.x - mu) * rs * gam[c] + bet[c]);
  o4.y = f2bf((xv.y - mu) * rs * gam[c + 1] + bet[c + 1]);
  o4.z = f2bf((xv.z - mu) * rs * gam[c + 2] + bet[c + 2]);
  o4.w = f2bf((xv.w - mu) * rs * gam[c + 3] + bet[c + 3]);
  *(u16x4*)(mln + row * 256 + c) = o4;
}

// ---------------------------------------------------------------------------
// Kernel 3 (REWRITTEN v3): fused QKVG.
// grid 512 (64-row blocks); wave = 64 rows x 64 cols; z-loop over 4 weights.
// lA[64][256], lB[256][64] both XOR-swizzled (byte ^= (row&7)<<4).
// T14 register prefetch of next B-chunk hides L2 latency under MFMA.
__global__ __launch_bounds__(256, 2) void k_qkvg(
    const u16* __restrict__ mln, const u16* __restrict__ wt,
    const float* __restrict__ bg, u16* __restrict__ q, u16* __restrict__ k,
    u16* __restrict__ v, u16* __restrict__ g) {
  __shared__ u16 lA[64 * 256];
  __shared__ u16 lB[256 * 64];
  const int t = threadIdx.x;
  const size_t row0 = (size_t)blockIdx.x * 64;
  // stage A once (swizzled)
  {
    const int r = t >> 2;
    const int swz = (r & 7) << 4;
    #pragma unroll
    for (int i = 0; i < 8; ++i) {
      const int c = (t & 3) * 64 + i * 8;
      *(u16x8*)((char*)lA + ((r * 512 + c * 2) ^ swz)) =
          *(const u16x8*)&mln[(row0 + r) * 256 + c];
    }
  }
  // prefetch epoch 0 (z=0, kt=0): thread t = row of Wt, 64 k = 128 B
  u16x8 pf[8];
  {
    const u16* src = wt + (size_t)t * 256;
    #pragma unroll
    for (int i = 0; i < 8; ++i) pf[i] = *(const u16x8*)&src[i * 8];
  }
  const int lane = t & 63, wave = t >> 6;
  const int wc = wave * 64;
  const int lrow = lane & 15, lk8 = (lane >> 4) * 8, lg4 = (lane >> 4) * 4;
  f32x4 acc[4][4];
  #pragma unroll 1
  for (int e = 0; e < 16; ++e) {
    const int z = e >> 2, kt = e & 3;
    if (kt == 0) {
      #pragma unroll
      for (int mm = 0; mm < 4; ++mm) {
        #pragma unroll
        for (int nn = 0; nn < 4; ++nn) acc[mm][nn] = (f32x4){0.f, 0.f, 0.f, 0.f};
      }
    }
    __syncthreads();   // prior epoch's lB reads complete
    {
      const int swz = (t & 7) << 4;
      #pragma unroll
      for (int i = 0; i < 8; ++i)
        *(u16x8*)((char*)lB + ((t * 128 + i * 16) ^ swz)) = pf[i];
    }
    if (e < 15) {      // prefetch next epoch while current computes
      const int e1 = e + 1;
      const u16* src = wt + (size_t)(e1 >> 2) * 65536 + (size_t)t * 256 + (e1 & 3) * 64;
      #pragma unroll
      for (int i = 0; i < 8; ++i) pf[i] = *(const u16x8*)&src[i * 8];
    }
    __syncthreads();   // lB (and, at e=0, lA) visible
    #pragma unroll
    for (int kk = 0; kk < 2; ++kk) {
      bf16x8 af[4], bfr[4];
      #pragma unroll
      for (int mm = 0; mm < 4; ++mm) {
        const int row = mm * 16 + lrow;
        af[mm] = *(const bf16x8*)((const char*)lA +
            ((row * 512 + (kt * 64 + kk * 32 + lk8) * 2) ^ ((row & 7) << 4)));
      }
      #pragma unroll
      for (int nn = 0; nn < 4; ++nn) {
        const int row = wc + nn * 16 + lrow;
        bfr[nn] = *(const bf16x8*)((const char*)lB +
            ((row * 128 + (kk * 32 + lk8) * 2) ^ ((row & 7) << 4)));
      }
      #pragma unroll
      for (int mm = 0; mm < 4; ++mm) {
        #pragma unroll
        for (int nn = 0; nn < 4; ++nn)
          acc[mm][nn] = __builtin_amdgcn_mfma_f32_16x16x32_bf16(
              af[mm], bfr[nn], acc[mm][nn], 0, 0, 0);
      }
    }
    if (kt == 3) {     // epilogue for weight z
      const float scale = (z == 0) ? 0.17677669529663687f : 1.0f;
      #pragma unroll
      for (int mm = 0; mm < 4; ++mm) {
        #pragma unroll
        for (int nn = 0; nn < 4; ++nn) {
          const int col = wc + nn * 16 + lrow;
          #pragma unroll
          for (int jr = 0; jr < 4; ++jr) {
            const size_t row = row0 + mm * 16 + lg4 + jr;
            const float val = acc[mm][nn][jr];
            if (z < 3) {
              u16* dst = (z == 0) ? q : (z == 1) ? k : v;
              const size_t si = row >> 8, ri = row & 255;
              const size_t hi = col >> 5, hdi = col & 31;
              dst[((si * 8 + hi) * 256 + ri) * 32 + hdi] = f2bf(val * scale);
            } else {
              const float x = val + bg[col];
              g[row * 256 + col] = f2bf(1.0f / (1.0f + __expf(-x)));
            }
          }
        }
      }
    }
  }
}

// ---------------------------------------------------------------------------
// Kernel 4: attention, swapped-QK 32x32x16, ONLINE fixed-shift softmax.
__global__ __launch_bounds__(256, 4) void k_attn(
    const u16* __restrict__ q, const u16* __restrict__ k,
    const u16* __restrict__ v, const u16* __restrict__ g,
    const float* __restrict__ pbp, const float* __restrict__ mask,
    u16* __restrict__ go) {
  __shared__ u16 lVt[32][276];   // V^T padded
  __shared__ float lMb[256];
  __shared__ float lL[4][32];
  const int bid = blockIdx.x;    // s*8+h
  const int si = bid >> 3, hi = bid & 7;
  const int t = threadIdx.x;
  const size_t base = (size_t)bid * 8192;

  lMb[t] = 1e9f * (mask[si * 256 + t] - 1.0f);
  #pragma unroll
  for (int it = 0; it < 4; ++it) {
    const int r = it * 64 + (t >> 2);
    const int hd0 = (t & 3) * 8;
    u16x8 vv = *(const u16x8*)&v[base + r * 32 + hd0];
    #pragma unroll
    for (int u = 0; u < 8; ++u) lVt[hd0 + u][r] = vv[u];
  }
  __syncthreads();

  const int lane = t & 63, wave = t >> 6;
  const int il = lane & 31, gh = lane >> 5;

  #pragma unroll 1
  for (int strip = 0; strip < 2; ++strip) {
    const int i0 = wave * 64 + strip * 32;
    bf16x8 qf[2];
    #pragma unroll
    for (int kk = 0; kk < 2; ++kk)
      qf[kk] = *(const bf16x8*)&q[base + (size_t)(i0 + il) * 32 + kk * 16 + gh * 8];
    const float* pbt = pbp + ((size_t)hi * 8 + (i0 >> 5)) * 8192 + lane * 16;

    f32x16 oacc0 = {}, oacc1 = {};
    float s0 = 0.f, s1 = 0.f, s2 = 0.f, s3 = 0.f;

    #pragma unroll 2
    for (int jt = 0; jt < 8; ++jt) {
      const float* pl = pbt + jt * 1024;
      // C = pb + mb - 16
      f32x16 c;
      #pragma unroll
      for (int qd = 0; qd < 4; ++qd) {
        const f32x4 pbq = *(const f32x4*)&pl[qd * 4];
        const int jb = jt * 32 + qd * 8 + gh * 4;
        #pragma unroll
        for (int c4 = 0; c4 < 4; ++c4)
          c[qd * 4 + c4] = pbq[c4] + lMb[jb + c4] - 16.0f;
      }
      const bf16x8 kf0 = *(const bf16x8*)&k[base + (size_t)(jt * 32 + il) * 32 + gh * 8];
      const bf16x8 kf1 = *(const bf16x8*)&k[base + (size_t)(jt * 32 + il) * 32 + 16 + gh * 8];
      c = __builtin_amdgcn_mfma_f32_32x32x16_bf16(kf0, qf[0], c, 0, 0, 0);
      c = __builtin_amdgcn_mfma_f32_32x32x16_bf16(kf1, qf[1], c, 0, 0, 0);
      // p = exp(s - 16); partial sums; pack bf16
      union PK { __bf16 h[4]; uint2 u; } pk[4];
      #pragma unroll
      for (int qd = 0; qd < 4; ++qd) {
        const float p0 = __expf(c[qd * 4 + 0]);
        const float p1 = __expf(c[qd * 4 + 1]);
        const float p2 = __expf(c[qd * 4 + 2]);
        const float p3 = __expf(c[qd * 4 + 3]);
        s0 += p0; s1 += p1; s2 += p2; s3 += p3;
        pk[qd].h[0] = (__bf16)p0; pk[qd].h[1] = (__bf16)p1;
        pk[qd].h[2] = (__bf16)p2; pk[qd].h[3] = (__bf16)p3;
      }
      // repack to PV A-fragments via lane^32 exchange
      const uint2 sA = gh ? pk[0].u : pk[1].u;
      uint2 rA; rA.x = __shfl_xor(sA.x, 32); rA.y = __shfl_xor(sA.y, 32);
      const uint2 sB = gh ? pk[2].u : pk[3].u;
      uint2 rB; rB.x = __shfl_xor(sB.x, 32); rB.y = __shfl_xor(sB.y, 32);
      union FR { uint2 u2[2]; bf16x8 v; } fa0, fa1;
      fa0.u2[0] = gh ? rA : pk[0].u;
      fa0.u2[1] = gh ? pk[1].u : rA;
      fa1.u2[0] = gh ? rB : pk[2].u;
      fa1.u2[1] = gh ? pk[3].u : rB;
      const bf16x8 vf0 = *(const bf16x8*)&lVt[il][jt * 32 + gh * 8];
      const bf16x8 vf1 = *(const bf16x8*)&lVt[il][jt * 32 + 16 + gh * 8];
      oacc0 = __builtin_amdgcn_mfma_f32_32x32x16_bf16(fa0.v, vf0, oacc0, 0, 0, 0);
      oacc1 = __builtin_amdgcn_mfma_f32_32x32x16_bf16(fa1.v, vf1, oacc1, 0, 0, 0);
    }

    float lsum = (s0 + s1) + (s2 + s3);
    lsum += __shfl_xor(lsum, 32);
    if (lane < 32) lL[wave][il] = 1.0f / lsum;

    // ---- epilogue: normalize, gate, store
    #pragma unroll
    for (int qd = 0; qd < 4; ++qd) {
      const f32x4 invq = *(const f32x4*)&lL[wave][qd * 8 + gh * 4];
      #pragma unroll
      for (int c4 = 0; c4 < 4; ++c4) {
        const int iloc = qd * 8 + gh * 4 + c4;
        const size_t row = (size_t)si * 256 + i0 + iloc;
        const int col = hi * 32 + il;
        const float ov = (oacc0[qd * 4 + c4] + oacc1[qd * 4 + c4]) * invq[c4];
        go[row * 256 + col] = f2bf(bf2f(g[row * 256 + col]) * ov);
      }
    }
  }
}

// ---------------------------------------------------------------------------
// Shared 128x128-tile GEMM core (pad 72).
__device__ __forceinline__ void gemm128_mfma(const u16* __restrict__ A,
                                             const u16* __restrict__ Bt,
                                             size_t arow0, int bcol0,
                                             f32x4 (&acc)[4][4]) {
  __shared__ u16 lA[128 * 72];
  __shared__ u16 lB[128 * 72];
  const int t = threadIdx.x;
  const int lane = t & 63;
  const int wr = ((t >> 6) >> 1) * 64;
  const int wc = ((t >> 6) & 1) * 64;
  const int lrow = lane & 15;
  const int lk8 = (lane >> 4) * 8;
  const int sr = t >> 3;
  const int sc = (t & 7) * 8;
  for (int kt = 0; kt < 4; ++kt) {
    __syncthreads();
    #pragma unroll
    for (int it = 0; it < 4; ++it) {
      const int r = it * 32 + sr;
      *(u16x8*)&lA[r * 72 + sc] =
          *(const u16x8*)&A[(arow0 + r) * 256 + kt * 64 + sc];
      *(u16x8*)&lB[r * 72 + sc] =
          *(const u16x8*)&Bt[(size_t)(bcol0 + r) * 256 + kt * 64 + sc];
    }
    __syncthreads();
    #pragma unroll
    for (int kk = 0; kk < 2; ++kk) {
      bf16x8 af[4], bfr[4];
      #pragma unroll
      for (int mm = 0; mm < 4; ++mm)
        af[mm] = *(const bf16x8*)&lA[(wr + mm * 16 + lrow) * 72 + kk * 32 + lk8];
      #pragma unroll
      for (int nn = 0; nn < 4; ++nn)
        bfr[nn] = *(const bf16x8*)&lB[(wc + nn * 16 + lrow) * 72 + kk * 32 + lk8];
      #pragma unroll
      for (int mm = 0; mm < 4; ++mm) {
        #pragma unroll
        for (int nn = 0; nn < 4; ++nn)
          acc[mm][nn] = __builtin_amdgcn_mfma_f32_16x16x32_bf16(
              af[mm], bfr[nn], acc[mm][nn], 0, 0, 0);
      }
    }
  }
}

// ---------------------------------------------------------------------------
// Kernel 5: out = go @ wo + bo  (fp32 out)
__global__ __launch_bounds__(256) void k_gemm_out(
    const u16* __restrict__ go, const u16* __restrict__ wot,
    const float* __restrict__ bo, float* __restrict__ out) {
  f32x4 acc[4][4] = {};
  const size_t arow0 = (size_t)blockIdx.x * 128;
  const int bcol0 = blockIdx.y * 128;
  gemm128_mfma(go, wot, arow0, bcol0, acc);
  const int lane = threadIdx.x & 63;
  const int wr = ((threadIdx.x >> 6) >> 1) * 64;
  const int wc = ((threadIdx.x >> 6) & 1) * 64;
  const int lrow = lane & 15, lg4 = (lane >> 4) * 4;
  #pragma unroll
  for (int mm = 0; mm < 4; ++mm) {
    #pragma unroll
    for (int nn = 0; nn < 4; ++nn) {
      const int col = bcol0 + wc + nn * 16 + lrow;
      #pragma unroll
      for (int jr = 0; jr < 4; ++jr) {
        const size_t row = arow0 + wr + mm * 16 + lg4 + jr;
        out[row * 256 + col] = acc[mm][nn][jr] + bo[col];
      }
    }
  }
}

// ---------------------------------------------------------------------------
extern "C" void kernel_launch(void* const* d_in, const int* in_sizes, int n_in,
                              void* d_out, int out_size, void* d_ws, size_t ws_size,
                              hipStream_t stream) {
  const float* m      = (const float*)d_in[0];
  const float* z      = (const float*)d_in[1];
  const float* mask   = (const float*)d_in[2];
  const float* ln_m_g = (const float*)d_in[3];
  const float* ln_m_b = (const float*)d_in[4];
  const float* ln_z_g = (const float*)d_in[5];
  const float* ln_z_b = (const float*)d_in[6];
  const float* w_z    = (const float*)d_in[7];
  const float* wq     = (const float*)d_in[8];
  const float* wk     = (const float*)d_in[9];
  const float* wv     = (const float*)d_in[10];
  const float* wg     = (const float*)d_in[11];
  const float* bg     = (const float*)d_in[12];
  const float* wo     = (const float*)d_in[13];
  const float* bo     = (const float*)d_in[14];
  float* out = (float*)d_out;

  char* w = (char*)d_ws;
  u16* wt    = (u16*)w;   w += (size_t)5 * 65536 * 2;
  float* pbp = (float*)w; w += (size_t)8 * 65536 * 4;
  u16* mln   = (u16*)w;   w += (size_t)32768 * 256 * 2;
  u16* qw    = (u16*)w;   w += (size_t)32768 * 256 * 2;
  u16* kw    = (u16*)w;   w += (size_t)32768 * 256 * 2;
  u16* vw    = (u16*)w;   w += (size_t)32768 * 256 * 2;
  u16* gw    = (u16*)w;   w += (size_t)32768 * 256 * 2;
  u16* gow   = mln;  // mln dead after k_qkvg; reuse for g*o

  k_prep_w   <<<80, 256, 0, stream>>>(wq, wk, wv, wg, wo, wt);
  k_pair_bias<<<4096, 256, 0, stream>>>(z, ln_z_g, ln_z_b, w_z, pbp);
  k_ln_m     <<<8192, 256, 0, stream>>>(m, ln_m_g, ln_m_b, mln);
  k_qkvg     <<<512, 256, 0, stream>>>(mln, wt, bg, qw, kw, vw, gw);
  k_attn     <<<1024, 256, 0, stream>>>(qw, kw, vw, gw, pbp, mask, gow);
  k_gemm_out <<<dim3(256, 2), 256, 0, stream>>>(gow, wt + (size_t)4 * 65536, bo, out);
}

// Round 6
// 146.421 us; speedup vs baseline: 1.1533x; 1.1533x over previous
//
#include <hip/hip_runtime.h>
#include <hip/hip_bf16.h>

typedef unsigned short u16;
typedef __bf16 bf16x8 __attribute__((ext_vector_type(8)));
typedef float f32x4 __attribute__((ext_vector_type(4)));
typedef float f32x16 __attribute__((ext_vector_type(16)));
typedef unsigned short u16x8 __attribute__((ext_vector_type(8)));
typedef unsigned short u16x4 __attribute__((ext_vector_type(4)));

// S=128, R=256, CM=256, CZ=128, H=8, HD=32

__device__ __forceinline__ u16 f2bf(float f) {
  union { float f; unsigned u; } v; v.f = f;
  unsigned r = v.u;
  r += 0x7fffu + ((r >> 16) & 1u);   // RNE
  return (u16)(r >> 16);
}
__device__ __forceinline__ float bf2f(u16 u) {
  union { unsigned u; float f; } v; v.u = ((unsigned)u) << 16;
  return v.f;
}

// ---------------------------------------------------------------------------
// Kernel 0: weights fp32 [k][n] -> bf16 packed in MFMA B-fragment order:
// wtp[z][n>>4][k>>5][lane][8] (u16 units: z*65536 + cblk*4096 + kblk*512 +
// lane*8), lane = (k_sub>>3)*16 + (n&15). One fragment = 1KB contiguous.
__global__ __launch_bounds__(256) void k_prep_w(
    const float* __restrict__ wq, const float* __restrict__ wk,
    const float* __restrict__ wv, const float* __restrict__ wg,
    const float* __restrict__ wo, u16* __restrict__ dst) {
  const int widx = blockIdx.x >> 4;
  const int tid = blockIdx.x & 15;
  const int ri = (tid >> 2) * 64;   // k-origin
  const int ci = (tid & 3) * 64;    // n-origin
  const float* src = (widx == 0) ? wq : (widx == 1) ? wk : (widx == 2) ? wv
                    : (widx == 3) ? wg : wo;
  __shared__ float lt[64][68];      // [k][n]
  const int t = threadIdx.x;
  {
    const int r = t >> 2;
    #pragma unroll
    for (int i = 0; i < 4; ++i) {
      const int c = (t & 3) * 16 + i * 4;
      *(float4*)&lt[r][c] = *(const float4*)&src[(ri + r) * 256 + ci + c];
    }
  }
  __syncthreads();
  #pragma unroll
  for (int cc = 0; cc < 2; ++cc) {
    const int c = t + cc * 256;     // chunk 0..511
    const int kb = c >> 8, cb = (c >> 6) & 3, lg = (c >> 4) & 3, lr = c & 15;
    u16x8 o;
    #pragma unroll
    for (int j = 0; j < 8; ++j) o[j] = f2bf(lt[kb * 32 + lg * 8 + j][cb * 16 + lr]);
    const size_t idx = (size_t)widx * 65536 + (size_t)((ci >> 4) + cb) * 4096
                     + (size_t)((ri >> 5) + kb) * 512 + (size_t)(lg * 16 + lr) * 8;
    *(u16x8*)&dst[idx] = o;
  }
}

// ---------------------------------------------------------------------------
// Kernel 1: pair bias -> PERMUTED layout pbp (MFMA-D order). Unchanged.
__global__ __launch_bounds__(256) void k_pair_bias(
    const float* __restrict__ z, const float* __restrict__ zg,
    const float* __restrict__ zb, const float* __restrict__ wz,
    float* __restrict__ pbp) {
  const int t = threadIdx.x;
  const int lane = t & 63, wave = t >> 6;
  const int ql = lane & 15;
  const int p = blockIdx.x * 16 + wave * 4 + (lane >> 4);   // i*256+j
  const float4 zv0 = *(const float4*)(z + (size_t)p * 128 + ql * 8);
  const float4 zv1 = *(const float4*)(z + (size_t)p * 128 + ql * 8 + 4);
  float s = zv0.x + zv0.y + zv0.z + zv0.w + zv1.x + zv1.y + zv1.z + zv1.w;
  float sq = zv0.x * zv0.x + zv0.y * zv0.y + zv0.z * zv0.z + zv0.w * zv0.w
           + zv1.x * zv1.x + zv1.y * zv1.y + zv1.z * zv1.z + zv1.w * zv1.w;
  #pragma unroll
  for (int o = 8; o > 0; o >>= 1) { s += __shfl_xor(s, o); sq += __shfl_xor(sq, o); }
  const float mu = s * 0.0078125f;
  const float var = sq * 0.0078125f - mu * mu;
  const float rs = rsqrtf(var + 1e-5f);
  const int c0 = ql * 8;
  float zn[8];
  zn[0] = (zv0.x - mu) * rs * zg[c0 + 0] + zb[c0 + 0];
  zn[1] = (zv0.y - mu) * rs * zg[c0 + 1] + zb[c0 + 1];
  zn[2] = (zv0.z - mu) * rs * zg[c0 + 2] + zb[c0 + 2];
  zn[3] = (zv0.w - mu) * rs * zg[c0 + 3] + zb[c0 + 3];
  zn[4] = (zv1.x - mu) * rs * zg[c0 + 4] + zb[c0 + 4];
  zn[5] = (zv1.y - mu) * rs * zg[c0 + 5] + zb[c0 + 5];
  zn[6] = (zv1.z - mu) * rs * zg[c0 + 6] + zb[c0 + 6];
  zn[7] = (zv1.w - mu) * rs * zg[c0 + 7] + zb[c0 + 7];
  float a[8] = {};
  #pragma unroll
  for (int i = 0; i < 8; ++i) {
    #pragma unroll
    for (int hh = 0; hh < 8; ++hh) a[hh] += zn[i] * wz[(c0 + i) * 8 + hh];
  }
  #pragma unroll
  for (int hh = 0; hh < 8; ++hh) {
    #pragma unroll
    for (int o = 8; o > 0; o >>= 1) a[hh] += __shfl_xor(a[hh], o);
  }
  if (ql == 0) {
    const int i = p >> 8, j = p & 255;
    const int strip = i >> 5, il = i & 31, jt = j >> 5, r = j & 31;
    const int gh = (r >> 2) & 1, qd = r >> 3, c4 = r & 3;
    const int off = (strip * 8 + jt) * 1024 + (gh * 32 + il) * 16 + qd * 4 + c4;
    #pragma unroll
    for (int hh = 0; hh < 8; ++hh) pbp[(size_t)hh * 65536 + off] = a[hh];
  }
}

// ---------------------------------------------------------------------------
// Kernel 2: LayerNorm(m) -> bf16 [32768][256]. Unchanged.
__global__ __launch_bounds__(256) void k_ln_m(
    const float* __restrict__ m, const float* __restrict__ gam,
    const float* __restrict__ bet, u16* __restrict__ mln) {
  const int lane = threadIdx.x & 63;
  const size_t row = (size_t)blockIdx.x * 4 + (threadIdx.x >> 6);
  const float4 xv = *(const float4*)(m + row * 256 + lane * 4);
  float s = xv.x + xv.y + xv.z + xv.w;
  float sq = xv.x * xv.x + xv.y * xv.y + xv.z * xv.z + xv.w * xv.w;
  #pragma unroll
  for (int o = 32; o > 0; o >>= 1) { s += __shfl_xor(s, o); sq += __shfl_xor(sq, o); }
  const float mu = s * 0.00390625f;
  const float var = sq * 0.00390625f - mu * mu;
  const float rs = rsqrtf(var + 1e-5f);
  const int c = lane * 4;
  u16x4 o4;
  o4.x = f2bf((xv.x - mu) * rs * gam[c] + bet[c]);
  o4.y = f2bf((xv.y - mu) * rs * gam[c + 1] + bet[c + 1]);
  o4.z = f2bf((xv.z - mu) * rs * gam[c + 2] + bet[c + 2]);
  o4.w = f2bf((xv.w - mu) * rs * gam[c + 3] + bet[c + 3]);
  *(u16x4*)(mln + row * 256 + c) = o4;
}

// ---------------------------------------------------------------------------
// Kernel 3 (v4): QKVG, barrier-free main loop.
// grid (512, 4): block = 64 rows x 256 cols of weight z=blockIdx.y.
// A staged once in swizzled LDS (ONE barrier); B fragments read directly
// from L2 in packed order with 1-deep register prefetch (no barrier crossed).
__global__ __launch_bounds__(256, 3) void k_qkvg(
    const u16* __restrict__ mln, const u16* __restrict__ wtp,
    const float* __restrict__ bg, u16* __restrict__ q, u16* __restrict__ k,
    u16* __restrict__ v, u16* __restrict__ g) {
  __shared__ u16 lA[64 * 256];
  const int t = threadIdx.x;
  const int z = blockIdx.y;
  const size_t row0 = (size_t)blockIdx.x * 64;
  {
    const int r = t >> 2;
    const int swz = (r & 7) << 4;
    #pragma unroll
    for (int i = 0; i < 8; ++i) {
      const int c = (t & 3) * 64 + i * 8;
      *(u16x8*)((char*)lA + ((r * 512 + c * 2) ^ swz)) =
          *(const u16x8*)&mln[(row0 + r) * 256 + c];
    }
  }
  __syncthreads();
  const int lane = t & 63, wave = t >> 6;
  const int lrow = lane & 15, lg = lane >> 4;
  const u16* Wz = wtp + (size_t)z * 65536 + (size_t)wave * 16384 + (size_t)lane * 8;
  f32x4 acc[4][4] = {};
  bf16x8 bcur[4], bnxt[4];
  #pragma unroll
  for (int nn = 0; nn < 4; ++nn) bcur[nn] = *(const bf16x8*)&Wz[nn * 4096];
  #pragma unroll
  for (int kc = 0; kc < 8; ++kc) {
    if (kc < 7) {
      #pragma unroll
      for (int nn = 0; nn < 4; ++nn)
        bnxt[nn] = *(const bf16x8*)&Wz[nn * 4096 + (kc + 1) * 512];
    }
    bf16x8 af[4];
    #pragma unroll
    for (int mm = 0; mm < 4; ++mm) {
      const int row = mm * 16 + lrow;
      af[mm] = *(const bf16x8*)((const char*)lA +
          ((row * 512 + kc * 64 + lg * 16) ^ ((row & 7) << 4)));
    }
    #pragma unroll
    for (int mm = 0; mm < 4; ++mm) {
      #pragma unroll
      for (int nn = 0; nn < 4; ++nn)
        acc[mm][nn] = __builtin_amdgcn_mfma_f32_16x16x32_bf16(
            af[mm], bcur[nn], acc[mm][nn], 0, 0, 0);
    }
    #pragma unroll
    for (int nn = 0; nn < 4; ++nn) bcur[nn] = bnxt[nn];
  }
  // epilogue
  const int wc = wave * 64, lg4 = lg * 4;
  const float scale = (z == 0) ? 0.17677669529663687f : 1.0f;
  #pragma unroll
  for (int mm = 0; mm < 4; ++mm) {
    #pragma unroll
    for (int nn = 0; nn < 4; ++nn) {
      const int col = wc + nn * 16 + lrow;
      #pragma unroll
      for (int jr = 0; jr < 4; ++jr) {
        const size_t row = row0 + mm * 16 + lg4 + jr;
        const float val = acc[mm][nn][jr];
        if (z < 3) {
          u16* dst = (z == 0) ? q : (z == 1) ? k : v;
          const size_t si = row >> 8, ri = row & 255;
          const size_t hi = col >> 5, hdi = col & 31;
          dst[((si * 8 + hi) * 256 + ri) * 32 + hdi] = f2bf(val * scale);
        } else {
          const float x = val + bg[col];
          g[row * 256 + col] = f2bf(1.0f / (1.0f + __expf(-x)));
        }
      }
    }
  }
}

// ---------------------------------------------------------------------------
// Kernel 4: attention, swapped-QK 32x32x16, ONLINE fixed-shift softmax.
// Unchanged from R4.
__global__ __launch_bounds__(256, 4) void k_attn(
    const u16* __restrict__ q, const u16* __restrict__ k,
    const u16* __restrict__ v, const u16* __restrict__ g,
    const float* __restrict__ pbp, const float* __restrict__ mask,
    u16* __restrict__ go) {
  __shared__ u16 lVt[32][276];   // V^T padded
  __shared__ float lMb[256];
  __shared__ float lL[4][32];
  const int bid = blockIdx.x;    // s*8+h
  const int si = bid >> 3, hi = bid & 7;
  const int t = threadIdx.x;
  const size_t base = (size_t)bid * 8192;

  lMb[t] = 1e9f * (mask[si * 256 + t] - 1.0f);
  #pragma unroll
  for (int it = 0; it < 4; ++it) {
    const int r = it * 64 + (t >> 2);
    const int hd0 = (t & 3) * 8;
    u16x8 vv = *(const u16x8*)&v[base + r * 32 + hd0];
    #pragma unroll
    for (int u = 0; u < 8; ++u) lVt[hd0 + u][r] = vv[u];
  }
  __syncthreads();

  const int lane = t & 63, wave = t >> 6;
  const int il = lane & 31, gh = lane >> 5;

  #pragma unroll 1
  for (int strip = 0; strip < 2; ++strip) {
    const int i0 = wave * 64 + strip * 32;
    bf16x8 qf[2];
    #pragma unroll
    for (int kk = 0; kk < 2; ++kk)
      qf[kk] = *(const bf16x8*)&q[base + (size_t)(i0 + il) * 32 + kk * 16 + gh * 8];
    const float* pbt = pbp + ((size_t)hi * 8 + (i0 >> 5)) * 8192 + lane * 16;

    f32x16 oacc0 = {}, oacc1 = {};
    float s0 = 0.f, s1 = 0.f, s2 = 0.f, s3 = 0.f;

    #pragma unroll 2
    for (int jt = 0; jt < 8; ++jt) {
      const float* pl = pbt + jt * 1024;
      // C = pb + mb - 16
      f32x16 c;
      #pragma unroll
      for (int qd = 0; qd < 4; ++qd) {
        const f32x4 pbq = *(const f32x4*)&pl[qd * 4];
        const int jb = jt * 32 + qd * 8 + gh * 4;
        #pragma unroll
        for (int c4 = 0; c4 < 4; ++c4)
          c[qd * 4 + c4] = pbq[c4] + lMb[jb + c4] - 16.0f;
      }
      const bf16x8 kf0 = *(const bf16x8*)&k[base + (size_t)(jt * 32 + il) * 32 + gh * 8];
      const bf16x8 kf1 = *(const bf16x8*)&k[base + (size_t)(jt * 32 + il) * 32 + 16 + gh * 8];
      c = __builtin_amdgcn_mfma_f32_32x32x16_bf16(kf0, qf[0], c, 0, 0, 0);
      c = __builtin_amdgcn_mfma_f32_32x32x16_bf16(kf1, qf[1], c, 0, 0, 0);
      // p = exp(s - 16); partial sums; pack bf16
      union PK { __bf16 h[4]; uint2 u; } pk[4];
      #pragma unroll
      for (int qd = 0; qd < 4; ++qd) {
        const float p0 = __expf(c[qd * 4 + 0]);
        const float p1 = __expf(c[qd * 4 + 1]);
        const float p2 = __expf(c[qd * 4 + 2]);
        const float p3 = __expf(c[qd * 4 + 3]);
        s0 += p0; s1 += p1; s2 += p2; s3 += p3;
        pk[qd].h[0] = (__bf16)p0; pk[qd].h[1] = (__bf16)p1;
        pk[qd].h[2] = (__bf16)p2; pk[qd].h[3] = (__bf16)p3;
      }
      // repack to PV A-fragments via lane^32 exchange
      const uint2 sA = gh ? pk[0].u : pk[1].u;
      uint2 rA; rA.x = __shfl_xor(sA.x, 32); rA.y = __shfl_xor(sA.y, 32);
      const uint2 sB = gh ? pk[2].u : pk[3].u;
      uint2 rB; rB.x = __shfl_xor(sB.x, 32); rB.y = __shfl_xor(sB.y, 32);
      union FR { uint2 u2[2]; bf16x8 v; } fa0, fa1;
      fa0.u2[0] = gh ? rA : pk[0].u;
      fa0.u2[1] = gh ? pk[1].u : rA;
      fa1.u2[0] = gh ? rB : pk[2].u;
      fa1.u2[1] = gh ? pk[3].u : rB;
      const bf16x8 vf0 = *(const bf16x8*)&lVt[il][jt * 32 + gh * 8];
      const bf16x8 vf1 = *(const bf16x8*)&lVt[il][jt * 32 + 16 + gh * 8];
      oacc0 = __builtin_amdgcn_mfma_f32_32x32x16_bf16(fa0.v, vf0, oacc0, 0, 0, 0);
      oacc1 = __builtin_amdgcn_mfma_f32_32x32x16_bf16(fa1.v, vf1, oacc1, 0, 0, 0);
    }

    float lsum = (s0 + s1) + (s2 + s3);
    lsum += __shfl_xor(lsum, 32);
    if (lane < 32) lL[wave][il] = 1.0f / lsum;

    // ---- epilogue: normalize, gate, store
    #pragma unroll
    for (int qd = 0; qd < 4; ++qd) {
      const f32x4 invq = *(const f32x4*)&lL[wave][qd * 8 + gh * 4];
      #pragma unroll
      for (int c4 = 0; c4 < 4; ++c4) {
        const int iloc = qd * 8 + gh * 4 + c4;
        const size_t row = (size_t)si * 256 + i0 + iloc;
        const int col = hi * 32 + il;
        const float ov = (oacc0[qd * 4 + c4] + oacc1[qd * 4 + c4]) * invq[c4];
        go[row * 256 + col] = f2bf(bf2f(g[row * 256 + col]) * ov);
      }
    }
  }
}

// ---------------------------------------------------------------------------
// Kernel 5 (v2): out = go @ wo + bo, barrier-free structure.
// grid 1024: block = 32 rows x 256 cols; wave = 32x64; wo from packed slot.
__global__ __launch_bounds__(256, 4) void k_gemm_out(
    const u16* __restrict__ go, const u16* __restrict__ wop,
    const float* __restrict__ bo, float* __restrict__ out) {
  __shared__ u16 lA[32 * 256];
  const int t = threadIdx.x;
  const size_t row0 = (size_t)blockIdx.x * 32;
  {
    const int r = t >> 3;
    const int swz = (r & 7) << 4;
    #pragma unroll
    for (int i = 0; i < 4; ++i) {
      const int c = (t & 7) * 32 + i * 8;
      *(u16x8*)((char*)lA + ((r * 512 + c * 2) ^ swz)) =
          *(const u16x8*)&go[(row0 + r) * 256 + c];
    }
  }
  __syncthreads();
  const int lane = t & 63, wave = t >> 6;
  const int lrow = lane & 15, lg = lane >> 4;
  const u16* Wz = wop + (size_t)wave * 16384 + (size_t)lane * 8;
  f32x4 acc[2][4] = {};
  bf16x8 bcur[4], bnxt[4];
  #pragma unroll
  for (int nn = 0; nn < 4; ++nn) bcur[nn] = *(const bf16x8*)&Wz[nn * 4096];
  #pragma unroll
  for (int kc = 0; kc < 8; ++kc) {
    if (kc < 7) {
      #pragma unroll
      for (int nn = 0; nn < 4; ++nn)
        bnxt[nn] = *(const bf16x8*)&Wz[nn * 4096 + (kc + 1) * 512];
    }
    bf16x8 af[2];
    #pragma unroll
    for (int mm = 0; mm < 2; ++mm) {
      const int row = mm * 16 + lrow;
      af[mm] = *(const bf16x8*)((const char*)lA +
          ((row * 512 + kc * 64 + lg * 16) ^ ((row & 7) << 4)));
    }
    #pragma unroll
    for (int mm = 0; mm < 2; ++mm) {
      #pragma unroll
      for (int nn = 0; nn < 4; ++nn)
        acc[mm][nn] = __builtin_amdgcn_mfma_f32_16x16x32_bf16(
            af[mm], bcur[nn], acc[mm][nn], 0, 0, 0);
    }
    #pragma unroll
    for (int nn = 0; nn < 4; ++nn) bcur[nn] = bnxt[nn];
  }
  const int wc = wave * 64, lg4 = lg * 4;
  #pragma unroll
  for (int mm = 0; mm < 2; ++mm) {
    #pragma unroll
    for (int nn = 0; nn < 4; ++nn) {
      const int col = wc + nn * 16 + lrow;
      #pragma unroll
      for (int jr = 0; jr < 4; ++jr) {
        const size_t row = row0 + mm * 16 + lg4 + jr;
        out[row * 256 + col] = acc[mm][nn][jr] + bo[col];
      }
    }
  }
}

// ---------------------------------------------------------------------------
extern "C" void kernel_launch(void* const* d_in, const int* in_sizes, int n_in,
                              void* d_out, int out_size, void* d_ws, size_t ws_size,
                              hipStream_t stream) {
  const float* m      = (const float*)d_in[0];
  const float* z      = (const float*)d_in[1];
  const float* mask   = (const float*)d_in[2];
  const float* ln_m_g = (const float*)d_in[3];
  const float* ln_m_b = (const float*)d_in[4];
  const float* ln_z_g = (const float*)d_in[5];
  const float* ln_z_b = (const float*)d_in[6];
  const float* w_z    = (const float*)d_in[7];
  const float* wq     = (const float*)d_in[8];
  const float* wk     = (const float*)d_in[9];
  const float* wv     = (const float*)d_in[10];
  const float* wg     = (const float*)d_in[11];
  const float* bg     = (const float*)d_in[12];
  const float* wo     = (const float*)d_in[13];
  const float* bo     = (const float*)d_in[14];
  float* out = (float*)d_out;

  char* w = (char*)d_ws;
  u16* wtp   = (u16*)w;   w += (size_t)5 * 65536 * 2;
  float* pbp = (float*)w; w += (size_t)8 * 65536 * 4;
  u16* mln   = (u16*)w;   w += (size_t)32768 * 256 * 2;
  u16* qw    = (u16*)w;   w += (size_t)32768 * 256 * 2;
  u16* kw    = (u16*)w;   w += (size_t)32768 * 256 * 2;
  u16* vw    = (u16*)w;   w += (size_t)32768 * 256 * 2;
  u16* gw    = (u16*)w;   w += (size_t)32768 * 256 * 2;
  u16* gow   = mln;  // mln dead after k_qkvg; reuse for g*o

  k_prep_w   <<<80, 256, 0, stream>>>(wq, wk, wv, wg, wo, wtp);
  k_pair_bias<<<4096, 256, 0, stream>>>(z, ln_z_g, ln_z_b, w_z, pbp);
  k_ln_m     <<<8192, 256, 0, stream>>>(m, ln_m_g, ln_m_b, mln);
  k_qkvg     <<<dim3(512, 4), 256, 0, stream>>>(mln, wtp, bg, qw, kw, vw, gw);
  k_attn     <<<1024, 256, 0, stream>>>(qw, kw, vw, gw, pbp, mask, gow);
  k_gemm_out <<<1024, 256, 0, stream>>>(gow, wtp + (size_t)4 * 65536, bo, out);
}

// Round 7
// 145.119 us; speedup vs baseline: 1.1637x; 1.0090x over previous
//
#include <hip/hip_runtime.h>
#include <hip/hip_bf16.h>

typedef unsigned short u16;
typedef __bf16 bf16x8 __attribute__((ext_vector_type(8)));
typedef float f32x4 __attribute__((ext_vector_type(4)));
typedef float f32x16 __attribute__((ext_vector_type(16)));
typedef unsigned short u16x8 __attribute__((ext_vector_type(8)));
typedef unsigned short u16x4 __attribute__((ext_vector_type(4)));

// S=128, R=256, CM=256, CZ=128, H=8, HD=32

__device__ __forceinline__ u16 f2bf(float f) {
  union { float f; unsigned u; } v; v.f = f;
  unsigned r = v.u;
  r += 0x7fffu + ((r >> 16) & 1u);   // RNE
  return (u16)(r >> 16);
}
__device__ __forceinline__ float bf2f(u16 u) {
  union { unsigned u; float f; } v; v.u = ((unsigned)u) << 16;
  return v.f;
}

// ---------------------------------------------------------------------------
// Kernel 0: weights fp32 [k][n] -> bf16 packed in MFMA B-fragment order:
// wtp[z][n>>4][k>>5][lane][8]. One fragment = 1KB contiguous.
__global__ __launch_bounds__(256) void k_prep_w(
    const float* __restrict__ wq, const float* __restrict__ wk,
    const float* __restrict__ wv, const float* __restrict__ wg,
    const float* __restrict__ wo, u16* __restrict__ dst) {
  const int widx = blockIdx.x >> 4;
  const int tid = blockIdx.x & 15;
  const int ri = (tid >> 2) * 64;   // k-origin
  const int ci = (tid & 3) * 64;    // n-origin
  const float* src = (widx == 0) ? wq : (widx == 1) ? wk : (widx == 2) ? wv
                    : (widx == 3) ? wg : wo;
  __shared__ float lt[64][68];      // [k][n]
  const int t = threadIdx.x;
  {
    const int r = t >> 2;
    #pragma unroll
    for (int i = 0; i < 4; ++i) {
      const int c = (t & 3) * 16 + i * 4;
      *(float4*)&lt[r][c] = *(const float4*)&src[(ri + r) * 256 + ci + c];
    }
  }
  __syncthreads();
  #pragma unroll
  for (int cc = 0; cc < 2; ++cc) {
    const int c = t + cc * 256;     // chunk 0..511
    const int kb = c >> 8, cb = (c >> 6) & 3, lg = (c >> 4) & 3, lr = c & 15;
    u16x8 o;
    #pragma unroll
    for (int j = 0; j < 8; ++j) o[j] = f2bf(lt[kb * 32 + lg * 8 + j][cb * 16 + lr]);
    const size_t idx = (size_t)widx * 65536 + (size_t)((ci >> 4) + cb) * 4096
                     + (size_t)((ri >> 5) + kb) * 512 + (size_t)(lg * 16 + lr) * 8;
    *(u16x8*)&dst[idx] = o;
  }
}

// ---------------------------------------------------------------------------
// Kernel 1: pair bias -> PERMUTED layout pbp (MFMA-D order). Unchanged.
__global__ __launch_bounds__(256) void k_pair_bias(
    const float* __restrict__ z, const float* __restrict__ zg,
    const float* __restrict__ zb, const float* __restrict__ wz,
    float* __restrict__ pbp) {
  const int t = threadIdx.x;
  const int lane = t & 63, wave = t >> 6;
  const int ql = lane & 15;
  const int p = blockIdx.x * 16 + wave * 4 + (lane >> 4);   // i*256+j
  const float4 zv0 = *(const float4*)(z + (size_t)p * 128 + ql * 8);
  const float4 zv1 = *(const float4*)(z + (size_t)p * 128 + ql * 8 + 4);
  float s = zv0.x + zv0.y + zv0.z + zv0.w + zv1.x + zv1.y + zv1.z + zv1.w;
  float sq = zv0.x * zv0.x + zv0.y * zv0.y + zv0.z * zv0.z + zv0.w * zv0.w
           + zv1.x * zv1.x + zv1.y * zv1.y + zv1.z * zv1.z + zv1.w * zv1.w;
  #pragma unroll
  for (int o = 8; o > 0; o >>= 1) { s += __shfl_xor(s, o); sq += __shfl_xor(sq, o); }
  const float mu = s * 0.0078125f;
  const float var = sq * 0.0078125f - mu * mu;
  const float rs = rsqrtf(var + 1e-5f);
  const int c0 = ql * 8;
  float zn[8];
  zn[0] = (zv0.x - mu) * rs * zg[c0 + 0] + zb[c0 + 0];
  zn[1] = (zv0.y - mu) * rs * zg[c0 + 1] + zb[c0 + 1];
  zn[2] = (zv0.z - mu) * rs * zg[c0 + 2] + zb[c0 + 2];
  zn[3] = (zv0.w - mu) * rs * zg[c0 + 3] + zb[c0 + 3];
  zn[4] = (zv1.x - mu) * rs * zg[c0 + 4] + zb[c0 + 4];
  zn[5] = (zv1.y - mu) * rs * zg[c0 + 5] + zb[c0 + 5];
  zn[6] = (zv1.z - mu) * rs * zg[c0 + 6] + zb[c0 + 6];
  zn[7] = (zv1.w - mu) * rs * zg[c0 + 7] + zb[c0 + 7];
  float a[8] = {};
  #pragma unroll
  for (int i = 0; i < 8; ++i) {
    #pragma unroll
    for (int hh = 0; hh < 8; ++hh) a[hh] += zn[i] * wz[(c0 + i) * 8 + hh];
  }
  #pragma unroll
  for (int hh = 0; hh < 8; ++hh) {
    #pragma unroll
    for (int o = 8; o > 0; o >>= 1) a[hh] += __shfl_xor(a[hh], o);
  }
  if (ql == 0) {
    const int i = p >> 8, j = p & 255;
    const int strip = i >> 5, il = i & 31, jt = j >> 5, r = j & 31;
    const int gh = (r >> 2) & 1, qd = r >> 3, c4 = r & 3;
    const int off = (strip * 8 + jt) * 1024 + (gh * 32 + il) * 16 + qd * 4 + c4;
    #pragma unroll
    for (int hh = 0; hh < 8; ++hh) pbp[(size_t)hh * 65536 + off] = a[hh];
  }
}

// ---------------------------------------------------------------------------
// Kernel 2: LayerNorm(m) -> bf16 [32768][256]. Unchanged.
__global__ __launch_bounds__(256) void k_ln_m(
    const float* __restrict__ m, const float* __restrict__ gam,
    const float* __restrict__ bet, u16* __restrict__ mln) {
  const int lane = threadIdx.x & 63;
  const size_t row = (size_t)blockIdx.x * 4 + (threadIdx.x >> 6);
  const float4 xv = *(const float4*)(m + row * 256 + lane * 4);
  float s = xv.x + xv.y + xv.z + xv.w;
  float sq = xv.x * xv.x + xv.y * xv.y + xv.z * xv.z + xv.w * xv.w;
  #pragma unroll
  for (int o = 32; o > 0; o >>= 1) { s += __shfl_xor(s, o); sq += __shfl_xor(sq, o); }
  const float mu = s * 0.00390625f;
  const float var = sq * 0.00390625f - mu * mu;
  const float rs = rsqrtf(var + 1e-5f);
  const int c = lane * 4;
  u16x4 o4;
  o4.x = f2bf((xv.x - mu) * rs * gam[c] + bet[c]);
  o4.y = f2bf((xv.y - mu) * rs * gam[c + 1] + bet[c + 1]);
  o4.z = f2bf((xv.z - mu) * rs * gam[c + 2] + bet[c + 2]);
  o4.w = f2bf((xv.w - mu) * rs * gam[c + 3] + bet[c + 3]);
  *(u16x4*)(mln + row * 256 + c) = o4;
}

// ---------------------------------------------------------------------------
// Kernel 3 (v5): QKVG. grid (512, 4): block = 64 rows x 256 cols, z = y.
// Staging: coalesced global read + conflict-free swizzled LDS write
// (octet covers 8 distinct 16B-groups). B from L2 with 2-deep reg prefetch.
__global__ __launch_bounds__(256, 4) void k_qkvg(
    const u16* __restrict__ mln, const u16* __restrict__ wtp,
    const float* __restrict__ bg, u16* __restrict__ q, u16* __restrict__ k,
    u16* __restrict__ v, u16* __restrict__ g) {
  __shared__ u16 lA[64 * 256];
  const int t = threadIdx.x;
  const int z = blockIdx.y;
  const size_t row0 = (size_t)blockIdx.x * 64;
  #pragma unroll
  for (int i = 0; i < 8; ++i) {
    const int r = i * 8 + (t >> 5);
    const int c = (t & 31) * 8;
    *(u16x8*)((char*)lA + ((r * 512 + c * 2) ^ ((r & 7) << 4))) =
        *(const u16x8*)&mln[(row0 + r) * 256 + c];
  }
  __syncthreads();
  const int lane = t & 63, wave = t >> 6;
  const int lrow = lane & 15, lg = lane >> 4;
  const u16* Wz = wtp + (size_t)z * 65536 + (size_t)wave * 16384 + (size_t)lane * 8;
  f32x4 acc[4][4] = {};
  bf16x8 b[3][4];
  #pragma unroll
  for (int nn = 0; nn < 4; ++nn) b[0][nn] = *(const bf16x8*)&Wz[nn * 4096];
  #pragma unroll
  for (int nn = 0; nn < 4; ++nn) b[1][nn] = *(const bf16x8*)&Wz[nn * 4096 + 512];
  #pragma unroll
  for (int kc = 0; kc < 8; ++kc) {
    if (kc < 6) {
      #pragma unroll
      for (int nn = 0; nn < 4; ++nn)
        b[(kc + 2) % 3][nn] = *(const bf16x8*)&Wz[nn * 4096 + (kc + 2) * 512];
    }
    bf16x8 af[4];
    #pragma unroll
    for (int mm = 0; mm < 4; ++mm) {
      const int row = mm * 16 + lrow;
      af[mm] = *(const bf16x8*)((const char*)lA +
          ((row * 512 + kc * 64 + lg * 16) ^ ((row & 7) << 4)));
    }
    const int cur = kc % 3;
    #pragma unroll
    for (int mm = 0; mm < 4; ++mm) {
      #pragma unroll
      for (int nn = 0; nn < 4; ++nn)
        acc[mm][nn] = __builtin_amdgcn_mfma_f32_16x16x32_bf16(
            af[mm], b[cur][nn], acc[mm][nn], 0, 0, 0);
    }
  }
  // epilogue
  const int wc = wave * 64, lg4 = lg * 4;
  const float scale = (z == 0) ? 0.17677669529663687f : 1.0f;
  #pragma unroll
  for (int mm = 0; mm < 4; ++mm) {
    #pragma unroll
    for (int nn = 0; nn < 4; ++nn) {
      const int col = wc + nn * 16 + lrow;
      #pragma unroll
      for (int jr = 0; jr < 4; ++jr) {
        const size_t row = row0 + mm * 16 + lg4 + jr;
        const float val = acc[mm][nn][jr];
        if (z < 3) {
          u16* dst = (z == 0) ? q : (z == 1) ? k : v;
          const size_t si = row >> 8, ri = row & 255;
          const size_t hi = col >> 5, hdi = col & 31;
          dst[((si * 8 + hi) * 256 + ri) * 32 + hdi] = f2bf(val * scale);
        } else {
          const float x = val + bg[col];
          g[row * 256 + col] = f2bf(1.0f / (1.0f + __expf(-x)));
        }
      }
    }
  }
}

// ---------------------------------------------------------------------------
// Kernel 4: attention, swapped-QK 32x32x16, ONLINE fixed-shift softmax.
// Unchanged from R4.
__global__ __launch_bounds__(256, 4) void k_attn(
    const u16* __restrict__ q, const u16* __restrict__ k,
    const u16* __restrict__ v, const u16* __restrict__ g,
    const float* __restrict__ pbp, const float* __restrict__ mask,
    u16* __restrict__ go) {
  __shared__ u16 lVt[32][276];   // V^T padded
  __shared__ float lMb[256];
  __shared__ float lL[4][32];
  const int bid = blockIdx.x;    // s*8+h
  const int si = bid >> 3, hi = bid & 7;
  const int t = threadIdx.x;
  const size_t base = (size_t)bid * 8192;

  lMb[t] = 1e9f * (mask[si * 256 + t] - 1.0f);
  #pragma unroll
  for (int it = 0; it < 4; ++it) {
    const int r = it * 64 + (t >> 2);
    const int hd0 = (t & 3) * 8;
    u16x8 vv = *(const u16x8*)&v[base + r * 32 + hd0];
    #pragma unroll
    for (int u = 0; u < 8; ++u) lVt[hd0 + u][r] = vv[u];
  }
  __syncthreads();

  const int lane = t & 63, wave = t >> 6;
  const int il = lane & 31, gh = lane >> 5;

  #pragma unroll 1
  for (int strip = 0; strip < 2; ++strip) {
    const int i0 = wave * 64 + strip * 32;
    bf16x8 qf[2];
    #pragma unroll
    for (int kk = 0; kk < 2; ++kk)
      qf[kk] = *(const bf16x8*)&q[base + (size_t)(i0 + il) * 32 + kk * 16 + gh * 8];
    const float* pbt = pbp + ((size_t)hi * 8 + (i0 >> 5)) * 8192 + lane * 16;

    f32x16 oacc0 = {}, oacc1 = {};
    float s0 = 0.f, s1 = 0.f, s2 = 0.f, s3 = 0.f;

    #pragma unroll 2
    for (int jt = 0; jt < 8; ++jt) {
      const float* pl = pbt + jt * 1024;
      // C = pb + mb - 16
      f32x16 c;
      #pragma unroll
      for (int qd = 0; qd < 4; ++qd) {
        const f32x4 pbq = *(const f32x4*)&pl[qd * 4];
        const int jb = jt * 32 + qd * 8 + gh * 4;
        #pragma unroll
        for (int c4 = 0; c4 < 4; ++c4)
          c[qd * 4 + c4] = pbq[c4] + lMb[jb + c4] - 16.0f;
      }
      const bf16x8 kf0 = *(const bf16x8*)&k[base + (size_t)(jt * 32 + il) * 32 + gh * 8];
      const bf16x8 kf1 = *(const bf16x8*)&k[base + (size_t)(jt * 32 + il) * 32 + 16 + gh * 8];
      c = __builtin_amdgcn_mfma_f32_32x32x16_bf16(kf0, qf[0], c, 0, 0, 0);
      c = __builtin_amdgcn_mfma_f32_32x32x16_bf16(kf1, qf[1], c, 0, 0, 0);
      // p = exp(s - 16); partial sums; pack bf16
      union PK { __bf16 h[4]; uint2 u; } pk[4];
      #pragma unroll
      for (int qd = 0; qd < 4; ++qd) {
        const float p0 = __expf(c[qd * 4 + 0]);
        const float p1 = __expf(c[qd * 4 + 1]);
        const float p2 = __expf(c[qd * 4 + 2]);
        const float p3 = __expf(c[qd * 4 + 3]);
        s0 += p0; s1 += p1; s2 += p2; s3 += p3;
        pk[qd].h[0] = (__bf16)p0; pk[qd].h[1] = (__bf16)p1;
        pk[qd].h[2] = (__bf16)p2; pk[qd].h[3] = (__bf16)p3;
      }
      // repack to PV A-fragments via lane^32 exchange
      const uint2 sA = gh ? pk[0].u : pk[1].u;
      uint2 rA; rA.x = __shfl_xor(sA.x, 32); rA.y = __shfl_xor(sA.y, 32);
      const uint2 sB = gh ? pk[2].u : pk[3].u;
      uint2 rB; rB.x = __shfl_xor(sB.x, 32); rB.y = __shfl_xor(sB.y, 32);
      union FR { uint2 u2[2]; bf16x8 v; } fa0, fa1;
      fa0.u2[0] = gh ? rA : pk[0].u;
      fa0.u2[1] = gh ? pk[1].u : rA;
      fa1.u2[0] = gh ? rB : pk[2].u;
      fa1.u2[1] = gh ? pk[3].u : rB;
      const bf16x8 vf0 = *(const bf16x8*)&lVt[il][jt * 32 + gh * 8];
      const bf16x8 vf1 = *(const bf16x8*)&lVt[il][jt * 32 + 16 + gh * 8];
      oacc0 = __builtin_amdgcn_mfma_f32_32x32x16_bf16(fa0.v, vf0, oacc0, 0, 0, 0);
      oacc1 = __builtin_amdgcn_mfma_f32_32x32x16_bf16(fa1.v, vf1, oacc1, 0, 0, 0);
    }

    float lsum = (s0 + s1) + (s2 + s3);
    lsum += __shfl_xor(lsum, 32);
    if (lane < 32) lL[wave][il] = 1.0f / lsum;

    // ---- epilogue: normalize, gate, store
    #pragma unroll
    for (int qd = 0; qd < 4; ++qd) {
      const f32x4 invq = *(const f32x4*)&lL[wave][qd * 8 + gh * 4];
      #pragma unroll
      for (int c4 = 0; c4 < 4; ++c4) {
        const int iloc = qd * 8 + gh * 4 + c4;
        const size_t row = (size_t)si * 256 + i0 + iloc;
        const int col = hi * 32 + il;
        const float ov = (oacc0[qd * 4 + c4] + oacc1[qd * 4 + c4]) * invq[c4];
        go[row * 256 + col] = f2bf(bf2f(g[row * 256 + col]) * ov);
      }
    }
  }
}

// ---------------------------------------------------------------------------
// Kernel 5 (v3): out = go @ wo + bo. grid 1024: 32 rows x 256 cols.
// Same staging + 2-deep prefetch as k_qkvg.
__global__ __launch_bounds__(256, 4) void k_gemm_out(
    const u16* __restrict__ go, const u16* __restrict__ wop,
    const float* __restrict__ bo, float* __restrict__ out) {
  __shared__ u16 lA[32 * 256];
  const int t = threadIdx.x;
  const size_t row0 = (size_t)blockIdx.x * 32;
  #pragma unroll
  for (int i = 0; i < 4; ++i) {
    const int r = i * 8 + (t >> 5);
    const int c = (t & 31) * 8;
    *(u16x8*)((char*)lA + ((r * 512 + c * 2) ^ ((r & 7) << 4))) =
        *(const u16x8*)&go[(row0 + r) * 256 + c];
  }
  __syncthreads();
  const int lane = t & 63, wave = t >> 6;
  const int lrow = lane & 15, lg = lane >> 4;
  const u16* Wz = wop + (size_t)wave * 16384 + (size_t)lane * 8;
  f32x4 acc[2][4] = {};
  bf16x8 b[3][4];
  #pragma unroll
  for (int nn = 0; nn < 4; ++nn) b[0][nn] = *(const bf16x8*)&Wz[nn * 4096];
  #pragma unroll
  for (int nn = 0; nn < 4; ++nn) b[1][nn] = *(const bf16x8*)&Wz[nn * 4096 + 512];
  #pragma unroll
  for (int kc = 0; kc < 8; ++kc) {
    if (kc < 6) {
      #pragma unroll
      for (int nn = 0; nn < 4; ++nn)
        b[(kc + 2) % 3][nn] = *(const bf16x8*)&Wz[nn * 4096 + (kc + 2) * 512];
    }
    bf16x8 af[2];
    #pragma unroll
    for (int mm = 0; mm < 2; ++mm) {
      const int row = mm * 16 + lrow;
      af[mm] = *(const bf16x8*)((const char*)lA +
          ((row * 512 + kc * 64 + lg * 16) ^ ((row & 7) << 4)));
    }
    const int cur = kc % 3;
    #pragma unroll
    for (int mm = 0; mm < 2; ++mm) {
      #pragma unroll
      for (int nn = 0; nn < 4; ++nn)
        acc[mm][nn] = __builtin_amdgcn_mfma_f32_16x16x32_bf16(
            af[mm], b[cur][nn], acc[mm][nn], 0, 0, 0);
    }
  }
  const int wc = wave * 64, lg4 = lg * 4;
  #pragma unroll
  for (int mm = 0; mm < 2; ++mm) {
    #pragma unroll
    for (int nn = 0; nn < 4; ++nn) {
      const int col = wc + nn * 16 + lrow;
      #pragma unroll
      for (int jr = 0; jr < 4; ++jr) {
        const size_t row = row0 + mm * 16 + lg4 + jr;
        out[row * 256 + col] = acc[mm][nn][jr] + bo[col];
      }
    }
  }
}

// ---------------------------------------------------------------------------
extern "C" void kernel_launch(void* const* d_in, const int* in_sizes, int n_in,
                              void* d_out, int out_size, void* d_ws, size_t ws_size,
                              hipStream_t stream) {
  const float* m      = (const float*)d_in[0];
  const float* z      = (const float*)d_in[1];
  const float* mask   = (const float*)d_in[2];
  const float* ln_m_g = (const float*)d_in[3];
  const float* ln_m_b = (const float*)d_in[4];
  const float* ln_z_g = (const float*)d_in[5];
  const float* ln_z_b = (const float*)d_in[6];
  const float* w_z    = (const float*)d_in[7];
  const float* wq     = (const float*)d_in[8];
  const float* wk     = (const float*)d_in[9];
  const float* wv     = (const float*)d_in[10];
  const float* wg     = (const float*)d_in[11];
  const float* bg     = (const float*)d_in[12];
  const float* wo     = (const float*)d_in[13];
  const float* bo     = (const float*)d_in[14];
  float* out = (float*)d_out;

  char* w = (char*)d_ws;
  u16* wtp   = (u16*)w;   w += (size_t)5 * 65536 * 2;
  float* pbp = (float*)w; w += (size_t)8 * 65536 * 4;
  u16* mln   = (u16*)w;   w += (size_t)32768 * 256 * 2;
  u16* qw    = (u16*)w;   w += (size_t)32768 * 256 * 2;
  u16* kw    = (u16*)w;   w += (size_t)32768 * 256 * 2;
  u16* vw    = (u16*)w;   w += (size_t)32768 * 256 * 2;
  u16* gw    = (u16*)w;   w += (size_t)32768 * 256 * 2;
  u16* gow   = mln;  // mln dead after k_qkvg; reuse for g*o

  k_prep_w   <<<80, 256, 0, stream>>>(wq, wk, wv, wg, wo, wtp);
  k_pair_bias<<<4096, 256, 0, stream>>>(z, ln_z_g, ln_z_b, w_z, pbp);
  k_ln_m     <<<8192, 256, 0, stream>>>(m, ln_m_g, ln_m_b, mln);
  k_qkvg     <<<dim3(512, 4), 256, 0, stream>>>(mln, wtp, bg, qw, kw, vw, gw);
  k_attn     <<<1024, 256, 0, stream>>>(qw, kw, vw, gw, pbp, mask, gow);
  k_gemm_out <<<1024, 256, 0, stream>>>(gow, wtp + (size_t)4 * 65536, bo, out);
}